// Round 1
// baseline (278.331 us; speedup 1.0000x reference)
//
#include <hip/hip_runtime.h>
#include <hip/hip_bf16.h>

#define HW    3136
#define HH    56
#define NCIN  256
#define MOUT  96    // 16 (x1) + 16 (x2) + 64 (x3)
#define NREL  16
#define NOUT  64
#define NG    8     // OUT/SH
#define KK    49

// ---------------- ws layout (in floats) ----------------
// wcat   : [96][256]        @ 0        (24576)
// bcat   : [96]             @ 24576    (96)
// s1/sh1 : [800] each       @ 24672 / 25472
// wc1t   : [800][8]         @ 26272    (6400)   (bn2-folded, transposed wcw1)
// b2f    : [8]              @ 32672
// xcat   : [B][96][HW]      @ 32768    (2408448)
// wmap   : [B][392][HW]     @ 2441216  (9834496)
#define OFF_WCAT  0
#define OFF_BCAT  24576
#define OFF_S1    24672
#define OFF_SH1   25472
#define OFF_WC1T  26272
#define OFF_B2F   32672
#define OFF_XCAT  32768
#define OFF_WMAP  2441216

// ---------------- precompute / repack ----------------
__global__ __launch_bounds__(256) void kprep(
    const float* __restrict__ w1, const float* __restrict__ b1,
    const float* __restrict__ w2, const float* __restrict__ b2,
    const float* __restrict__ w3, const float* __restrict__ b3,
    const float* __restrict__ bn1g, const float* __restrict__ bn1b,
    const float* __restrict__ bn1m, const float* __restrict__ bn1v,
    const float* __restrict__ wcw1,
    const float* __restrict__ bn2g, const float* __restrict__ bn2b,
    const float* __restrict__ bn2m, const float* __restrict__ bn2v,
    float* __restrict__ ws)
{
    int idx = blockIdx.x * 256 + threadIdx.x;
    // wcat [96][256]
    if (idx < 24576) {
        int o = idx >> 8, c = idx & 255;
        float v = (o < 16) ? w1[o * 256 + c]
                : (o < 32) ? w2[(o - 16) * 256 + c]
                           : w3[(o - 32) * 256 + c];
        ws[OFF_WCAT + idx] = v;
    }
    int i2 = idx - 24576;   // bcat [96]
    if (i2 >= 0 && i2 < 96) {
        float v = (i2 < 16) ? b1[i2] : (i2 < 32) ? b2[i2 - 16] : b3[i2 - 32];
        ws[OFF_BCAT + i2] = v;
    }
    int i3 = idx - 24672;   // bn1 scale/shift [800]
    if (i3 >= 0 && i3 < 800) {
        float s = bn1g[i3] / sqrtf(bn1v[i3] + 1e-5f);
        ws[OFF_S1 + i3]  = s;
        ws[OFF_SH1 + i3] = bn1b[i3] - bn1m[i3] * s;
    }
    int i4 = idx - 25472;   // wc1t [800][8] = wcw1[g][j] * bn2scale[g]
    if (i4 >= 0 && i4 < 6400) {
        int j = i4 >> 3, g = i4 & 7;
        float s2 = bn2g[g] / sqrtf(bn2v[g] + 1e-5f);
        ws[OFF_WC1T + i4] = wcw1[g * 800 + j] * s2;
    }
    int i5 = idx - 31872;   // b2f [8]
    if (i5 >= 0 && i5 < 8) {
        float s2 = bn2g[i5] / sqrtf(bn2v[i5] + 1e-5f);
        ws[OFF_B2F + i5] = bn2b[i5] - bn2m[i5] * s2;
    }
}

// ---------------- fused 1x1 convs: xcat[b][96][hw] ----------------
// block: 256 threads = 8 o-groups x 32 px-pairs; covers 64 px, all 96 out ch.
__global__ __launch_bounds__(256) void kconvA(
    const float* __restrict__ x, const float* __restrict__ wcat,
    const float* __restrict__ bcat, float* __restrict__ xcat)
{
    __shared__ float wl[64][100];  // [c][o] padded (+4 to avoid write conflicts)
    __shared__ float xl[64][64];   // [c][px]
    const int tid = threadIdx.x;
    const int bi  = blockIdx.x;
    const int b   = bi / 49;
    const int hw0 = (bi % 49) * 64;
    const int pxp = tid & 31;
    const int og  = tid >> 5;       // 0..7
    const int obase = og * 12;

    float acc0[12], acc1[12];
#pragma unroll
    for (int o = 0; o < 12; ++o) {
        float bv = bcat[obase + o];
        acc0[o] = bv; acc1[o] = bv;
    }

    const float* xb = x + (size_t)b * NCIN * HW + hw0;

    for (int cc = 0; cc < 4; ++cc) {
        __syncthreads();
        // stage weight chunk: wl[c][o] = wcat[o*256 + cc*64 + c]
#pragma unroll
        for (int t = 0; t < 24; ++t) {
            int idx = t * 256 + tid;        // 0..6143
            int o = idx >> 6;
            int c = idx & 63;
            wl[c][o] = wcat[o * NCIN + cc * 64 + c];
        }
        // stage x chunk (coalesced 64-px rows)
#pragma unroll
        for (int i = 0; i < 16; ++i) {
            int c = i * 4 + (tid >> 6);
            xl[c][tid & 63] = xb[(size_t)(cc * 64 + c) * HW + (tid & 63)];
        }
        __syncthreads();
#pragma unroll 4
        for (int c = 0; c < 64; ++c) {
            float xv0 = xl[c][pxp];
            float xv1 = xl[c][pxp + 32];
            float wv[12];
            *(float4*)&wv[0] = *(const float4*)&wl[c][obase];
            *(float4*)&wv[4] = *(const float4*)&wl[c][obase + 4];
            *(float4*)&wv[8] = *(const float4*)&wl[c][obase + 8];
#pragma unroll
            for (int o = 0; o < 12; ++o) {
                acc0[o] = fmaf(xv0, wv[o], acc0[o]);
                acc1[o] = fmaf(xv1, wv[o], acc1[o]);
            }
        }
    }

    float* outp = xcat + (size_t)b * MOUT * HW + hw0;
#pragma unroll
    for (int o = 0; o < 12; ++o) {
        outp[(size_t)(obase + o) * HW + pxp]      = acc0[o];
        outp[(size_t)(obase + o) * HW + pxp + 32] = acc1[o];
    }
}

// reflect index helper for the x2 path (reflect 2 then zero-pad 4)
__device__ __forceinline__ int refl(int p) {
    return p < 0 ? -p : (p > 55 ? 110 - p : p);
}

// ---------------- wmap: per-pixel attention weights ----------------
__global__ __launch_bounds__(256) void kwmap(
    const float* __restrict__ xcat, const float* __restrict__ s1,
    const float* __restrict__ sh1, const float* __restrict__ wc1t,
    const float* __restrict__ b2f, const float* __restrict__ wcw2,
    const float* __restrict__ bcw2, float* __restrict__ wmap)
{
    const int pid = blockIdx.x * 256 + threadIdx.x;
    if (pid >= 8 * HW) return;
    const int b  = pid / HW;
    const int n  = pid - b * HW;
    const int y  = n / HH;
    const int xx = n - y * HH;

    const float* x1 = xcat + (size_t)b * MOUT * HW;
    const float* x2 = x1 + 16 * HW;

    float acc[8];
#pragma unroll
    for (int g = 0; g < 8; ++g) acc[g] = b2f[g];

    // x1 contribution (cat channels 0..15)
#pragma unroll
    for (int r = 0; r < 16; ++r) {
        float v = x1[r * HW + n];
        v = fmaxf(fmaf(v, s1[r], sh1[r]), 0.f);
        const float* wr = wc1t + r * 8;
#pragma unroll
        for (int g = 0; g < 8; ++g) acc[g] = fmaf(v, wr[g], acc[g]);
    }

    // x2 dilated window (cat channels 16 + r*49 + kk)
#pragma unroll 1
    for (int i = 0; i < 7; ++i) {
        int p  = y + 2 * i - 6;
        int py = refl(p);
        bool zr = (p < -2) | (p > 57);
#pragma unroll 1
        for (int jj = 0; jj < 7; ++jj) {
            int q  = xx + 2 * jj - 6;
            int px = refl(q);
            bool zc = zr | (q < -2) | (q > 57);
            int off = py * HH + px;
            int kk  = i * 7 + jj;
#pragma unroll
            for (int r = 0; r < 16; ++r) {
                int j = 16 + r * KK + kk;
                float v = zc ? 0.f : x2[r * HW + off];
                v = fmaxf(fmaf(v, s1[j], sh1[j]), 0.f);
                const float* wr = wc1t + j * 8;
#pragma unroll
                for (int g = 0; g < 8; ++g) acc[g] = fmaf(v, wr[g], acc[g]);
            }
        }
    }

    float t[8];
#pragma unroll
    for (int g = 0; g < 8; ++g) t[g] = fmaxf(acc[g], 0.f);

    float* wout = wmap + (size_t)b * 392 * HW + n;
#pragma unroll 4
    for (int qq = 0; qq < 392; ++qq) {
        const float* wr = wcw2 + qq * 8;
        float s = bcw2[qq];
#pragma unroll
        for (int g = 0; g < 8; ++g) s = fmaf(t[g], wr[g], s);
        wout[(size_t)qq * HW] = s;
    }
}

// ---------------- aggregation: out[b][64][hw] ----------------
__global__ __launch_bounds__(256) void kaggr(
    const float* __restrict__ xcat, const float* __restrict__ wmap,
    float* __restrict__ out)
{
    const int n = blockIdx.x * 256 + threadIdx.x;
    if (n >= HW) return;
    const int g = blockIdx.y;
    const int b = blockIdx.z;
    const int y  = n / HH;
    const int xx = n - y * HH;

    const float* x3 = xcat + ((size_t)b * MOUT + 32 + g * 8) * HW;
    const float* wm = wmap + (size_t)(b * NG + g) * KK * HW + n;

    float acc[8];
#pragma unroll
    for (int s = 0; s < 8; ++s) acc[s] = 0.f;

#pragma unroll 1
    for (int i = 0; i < 7; ++i) {
        int p  = y + 2 * i - 6;
        int py = refl(p);   // reflect-6: always in range
#pragma unroll
        for (int jj = 0; jj < 7; ++jj) {
            int q  = xx + 2 * jj - 6;
            int px = refl(q);
            int off = py * HH + px;
            float wv = wm[(size_t)(i * 7 + jj) * HW];
#pragma unroll
            for (int s = 0; s < 8; ++s)
                acc[s] = fmaf(x3[s * HW + off], wv, acc[s]);
        }
    }

    float* op = out + ((size_t)b * NOUT + g * 8) * HW + n;
#pragma unroll
    for (int s = 0; s < 8; ++s) op[s * HW] = acc[s];
}

extern "C" void kernel_launch(void* const* d_in, const int* in_sizes, int n_in,
                              void* d_out, int out_size, void* d_ws, size_t ws_size,
                              hipStream_t stream) {
    const float* x    = (const float*)d_in[0];
    const float* w1   = (const float*)d_in[1];
    const float* b1   = (const float*)d_in[2];
    const float* w2   = (const float*)d_in[3];
    const float* b2   = (const float*)d_in[4];
    const float* w3   = (const float*)d_in[5];
    const float* b3   = (const float*)d_in[6];
    const float* bn1g = (const float*)d_in[7];
    const float* bn1b = (const float*)d_in[8];
    const float* bn1m = (const float*)d_in[9];
    const float* bn1v = (const float*)d_in[10];
    const float* wcw1 = (const float*)d_in[11];
    const float* bn2g = (const float*)d_in[12];
    const float* bn2b = (const float*)d_in[13];
    const float* bn2m = (const float*)d_in[14];
    const float* bn2v = (const float*)d_in[15];
    const float* wcw2 = (const float*)d_in[16];
    const float* bcw2 = (const float*)d_in[17];

    float* ws = (float*)d_ws;
    float* wcat = ws + OFF_WCAT;
    float* bcat = ws + OFF_BCAT;
    float* s1   = ws + OFF_S1;
    float* sh1  = ws + OFF_SH1;
    float* wc1t = ws + OFF_WC1T;
    float* b2f  = ws + OFF_B2F;
    float* xcat = ws + OFF_XCAT;
    float* wmap = ws + OFF_WMAP;

    kprep<<<125, 256, 0, stream>>>(w1, b1, w2, b2, w3, b3,
                                   bn1g, bn1b, bn1m, bn1v, wcw1,
                                   bn2g, bn2b, bn2m, bn2v, ws);
    kconvA<<<392, 256, 0, stream>>>(x, wcat, bcat, xcat);
    kwmap<<<98, 256, 0, stream>>>(xcat, s1, sh1, wc1t, b2f, wcw2, bcw2, wmap);
    dim3 gC(13, 8, 8);
    kaggr<<<gC, 256, 0, stream>>>(xcat, wmap, (float*)d_out);
}

// Round 2
// 86.623 us; speedup vs baseline: 3.2131x; 3.2131x over previous
//
#include <hip/hip_runtime.h>
#include <hip/hip_bf16.h>

#define HW    3136
#define HH    56
#define NCIN  256
#define MOUT  96    // 16 (x1) + 16 (x2) + 64 (x3)
#define NREL  16
#define NOUT  64
#define NG    8     // OUT/SH
#define KK    49

// ---------------- ws layout (in floats) ----------------
// wcat   : [96][256]        @ 0        (24576)
// bcat   : [96]             @ 24576    (96)
// s1/sh1 : [800] each       @ 24672 / 25472
// wc1t   : [800][8]         @ 26272    (6400)   (bn2-folded, transposed wcw1)
// b2f    : [8]              @ 32672
// xcat   : [B][96][HW]      @ 32768    (2408448)
// tbuf   : [B][8][HW]       @ 2441216  (200704)
#define OFF_WCAT  0
#define OFF_BCAT  24576
#define OFF_S1    24672
#define OFF_SH1   25472
#define OFF_WC1T  26272
#define OFF_B2F   32672
#define OFF_XCAT  32768
#define OFF_TBUF  2441216

// ---------------- precompute / repack ----------------
__global__ __launch_bounds__(256) void kprep(
    const float* __restrict__ w1, const float* __restrict__ b1,
    const float* __restrict__ w2, const float* __restrict__ b2,
    const float* __restrict__ w3, const float* __restrict__ b3,
    const float* __restrict__ bn1g, const float* __restrict__ bn1b,
    const float* __restrict__ bn1m, const float* __restrict__ bn1v,
    const float* __restrict__ wcw1,
    const float* __restrict__ bn2g, const float* __restrict__ bn2b,
    const float* __restrict__ bn2m, const float* __restrict__ bn2v,
    float* __restrict__ ws)
{
    int idx = blockIdx.x * 256 + threadIdx.x;
    if (idx < 24576) {
        int o = idx >> 8, c = idx & 255;
        float v = (o < 16) ? w1[o * 256 + c]
                : (o < 32) ? w2[(o - 16) * 256 + c]
                           : w3[(o - 32) * 256 + c];
        ws[OFF_WCAT + idx] = v;
    }
    int i2 = idx - 24576;
    if (i2 >= 0 && i2 < 96) {
        float v = (i2 < 16) ? b1[i2] : (i2 < 32) ? b2[i2 - 16] : b3[i2 - 32];
        ws[OFF_BCAT + i2] = v;
    }
    int i3 = idx - 24672;
    if (i3 >= 0 && i3 < 800) {
        float s = bn1g[i3] / sqrtf(bn1v[i3] + 1e-5f);
        ws[OFF_S1 + i3]  = s;
        ws[OFF_SH1 + i3] = bn1b[i3] - bn1m[i3] * s;
    }
    int i4 = idx - 25472;
    if (i4 >= 0 && i4 < 6400) {
        int j = i4 >> 3, g = i4 & 7;
        float s2 = bn2g[g] / sqrtf(bn2v[g] + 1e-5f);
        ws[OFF_WC1T + i4] = wcw1[g * 800 + j] * s2;
    }
    int i5 = idx - 31872;
    if (i5 >= 0 && i5 < 8) {
        float s2 = bn2g[i5] / sqrtf(bn2v[i5] + 1e-5f);
        ws[OFF_B2F + i5] = bn2b[i5] - bn2m[i5] * s2;
    }
}

// ---------------- fused 1x1 convs: xcat[b][96][hw] ----------------
__global__ __launch_bounds__(256) void kconvA(
    const float* __restrict__ x, const float* __restrict__ wcat,
    const float* __restrict__ bcat, float* __restrict__ xcat)
{
    __shared__ float wl[64][100];
    __shared__ float xl[64][64];
    const int tid = threadIdx.x;
    const int bi  = blockIdx.x;
    const int b   = bi / 49;
    const int hw0 = (bi % 49) * 64;
    const int pxp = tid & 31;
    const int og  = tid >> 5;
    const int obase = og * 12;

    float acc0[12], acc1[12];
#pragma unroll
    for (int o = 0; o < 12; ++o) {
        float bv = bcat[obase + o];
        acc0[o] = bv; acc1[o] = bv;
    }

    const float* xb = x + (size_t)b * NCIN * HW + hw0;

    for (int cc = 0; cc < 4; ++cc) {
        __syncthreads();
#pragma unroll
        for (int t = 0; t < 24; ++t) {
            int idx = t * 256 + tid;
            int o = idx >> 6;
            int c = idx & 63;
            wl[c][o] = wcat[o * NCIN + cc * 64 + c];
        }
#pragma unroll
        for (int i = 0; i < 16; ++i) {
            int c = i * 4 + (tid >> 6);
            xl[c][tid & 63] = xb[(size_t)(cc * 64 + c) * HW + (tid & 63)];
        }
        __syncthreads();
#pragma unroll 4
        for (int c = 0; c < 64; ++c) {
            float xv0 = xl[c][pxp];
            float xv1 = xl[c][pxp + 32];
            float wv[12];
            *(float4*)&wv[0] = *(const float4*)&wl[c][obase];
            *(float4*)&wv[4] = *(const float4*)&wl[c][obase + 4];
            *(float4*)&wv[8] = *(const float4*)&wl[c][obase + 8];
#pragma unroll
            for (int o = 0; o < 12; ++o) {
                acc0[o] = fmaf(xv0, wv[o], acc0[o]);
                acc1[o] = fmaf(xv1, wv[o], acc1[o]);
            }
        }
    }

    float* outp = xcat + (size_t)b * MOUT * HW + hw0;
#pragma unroll
    for (int o = 0; o < 12; ++o) {
        outp[(size_t)(obase + o) * HW + pxp]      = acc0[o];
        outp[(size_t)(obase + o) * HW + pxp + 32] = acc1[o];
    }
}

__device__ __forceinline__ int refl(int p) {
    return p < 0 ? -p : (p > 55 ? 110 - p : p);
}

// ---------------- t: per-pixel 8-dim bottleneck ----------------
// 512 threads = 8 waves; block covers 64 consecutive pixels (lane = pixel).
// Wave w handles tap-units u in [50w/8, 50(w+1)/8): u=0 -> x1 (16 taps),
// u=1..49 -> x2 window tap kk=u-1 (16 taps each). LDS tree-reduce at end.
__global__ __launch_bounds__(512) void kwmap_t(
    const float* __restrict__ xcat, const float* __restrict__ s1,
    const float* __restrict__ sh1, const float* __restrict__ wc1t,
    const float* __restrict__ b2f, float* __restrict__ tbuf)
{
    __shared__ float red[8][8][64];   // [wave][g][px]
    const int tid = threadIdx.x;
    const int w   = tid >> 6;
    const int l   = tid & 63;
    const int pxg = blockIdx.x * 64;      // global pixel (b*HW + n), 64 | HW
    const int b   = pxg / HW;
    const int nb  = pxg - b * HW;         // block base within image
    const int n   = nb + l;
    const int y   = n / HH;
    const int xx  = n - y * HH;

    const float* x1 = xcat + (size_t)b * MOUT * HW;
    const float* x2 = x1 + 16 * HW;

    float acc[8];
#pragma unroll
    for (int g = 0; g < 8; ++g) acc[g] = 0.f;

    const int u0 = (50 * w) >> 3;
    const int u1 = (50 * (w + 1)) >> 3;

#pragma unroll 1
    for (int u = u0; u < u1; ++u) {
        if (u == 0) {
#pragma unroll
            for (int r = 0; r < 16; ++r) {
                float v = x1[r * HW + n];
                v = fmaxf(fmaf(v, s1[r], sh1[r]), 0.f);
                const float* wr = wc1t + r * 8;
#pragma unroll
                for (int g = 0; g < 8; ++g) acc[g] = fmaf(v, wr[g], acc[g]);
            }
        } else {
            const int kk = __builtin_amdgcn_readfirstlane(u - 1);
            const int i  = kk / 7;
            const int jj = kk - i * 7;
            int p = y + 2 * i - 6;
            int q = xx + 2 * jj - 6;
            bool z = (p < -2) | (p > 57) | (q < -2) | (q > 57);
            int off = refl(p) * HH + refl(q);
            const float* x2o = x2 + off;
#pragma unroll
            for (int r = 0; r < 16; ++r) {
                const int j = 16 + r * KK + kk;   // wave-uniform -> scalar loads
                float v = z ? 0.f : x2o[(size_t)r * HW];
                v = fmaxf(fmaf(v, s1[j], sh1[j]), 0.f);
                const float* wr = wc1t + j * 8;
#pragma unroll
                for (int g = 0; g < 8; ++g) acc[g] = fmaf(v, wr[g], acc[g]);
            }
        }
    }

#pragma unroll
    for (int g = 0; g < 8; ++g) red[w][g][l] = acc[g];
    __syncthreads();

    // 512 threads <-> 512 (g, px) pairs
    {
        const int g  = tid >> 6;
        const int px = tid & 63;
        float s = b2f[g];
#pragma unroll
        for (int ww = 0; ww < 8; ++ww) s += red[ww][g][px];
        s = fmaxf(s, 0.f);
        tbuf[((size_t)b * 8 + g) * HW + nb + px] = s;
    }
}

// ---------------- fused wmap + aggregation ----------------
__global__ __launch_bounds__(256) void kaggr(
    const float* __restrict__ xcat, const float* __restrict__ tbuf,
    const float* __restrict__ wcw2, const float* __restrict__ bcw2,
    float* __restrict__ out)
{
    const int n = blockIdx.x * 256 + threadIdx.x;
    if (n >= HW) return;
    const int g = blockIdx.y;
    const int b = blockIdx.z;
    const int y  = n / HH;
    const int xx = n - y * HH;

    const float* x3 = xcat + ((size_t)b * MOUT + 32 + g * 8) * HW;

    float t[8];
#pragma unroll
    for (int e = 0; e < 8; ++e) t[e] = tbuf[((size_t)b * 8 + e) * HW + n];

    float acc[8];
#pragma unroll
    for (int s = 0; s < 8; ++s) acc[s] = 0.f;

    const float* wrow = wcw2 + (size_t)g * KK * 8;  // uniform -> scalar loads
    const float* brow = bcw2 + g * KK;

#pragma unroll 1
    for (int i = 0; i < 7; ++i) {
        int p  = y + 2 * i - 6;
        int py = refl(p);
#pragma unroll
        for (int jj = 0; jj < 7; ++jj) {
            int q  = xx + 2 * jj - 6;
            int px = refl(q);
            int off = py * HH + px;
            int k   = i * 7 + jj;
            float wv = brow[k];
#pragma unroll
            for (int e = 0; e < 8; ++e) wv = fmaf(t[e], wrow[k * 8 + e], wv);
#pragma unroll
            for (int s = 0; s < 8; ++s)
                acc[s] = fmaf(x3[s * HW + off], wv, acc[s]);
        }
    }

    float* op = out + ((size_t)b * NOUT + g * 8) * HW + n;
#pragma unroll
    for (int s = 0; s < 8; ++s) op[s * HW] = acc[s];
}

extern "C" void kernel_launch(void* const* d_in, const int* in_sizes, int n_in,
                              void* d_out, int out_size, void* d_ws, size_t ws_size,
                              hipStream_t stream) {
    const float* x    = (const float*)d_in[0];
    const float* w1   = (const float*)d_in[1];
    const float* b1   = (const float*)d_in[2];
    const float* w2   = (const float*)d_in[3];
    const float* b2   = (const float*)d_in[4];
    const float* w3   = (const float*)d_in[5];
    const float* b3   = (const float*)d_in[6];
    const float* bn1g = (const float*)d_in[7];
    const float* bn1b = (const float*)d_in[8];
    const float* bn1m = (const float*)d_in[9];
    const float* bn1v = (const float*)d_in[10];
    const float* wcw1 = (const float*)d_in[11];
    const float* bn2g = (const float*)d_in[12];
    const float* bn2b = (const float*)d_in[13];
    const float* bn2m = (const float*)d_in[14];
    const float* bn2v = (const float*)d_in[15];
    const float* wcw2 = (const float*)d_in[16];
    const float* bcw2 = (const float*)d_in[17];

    float* ws = (float*)d_ws;
    float* wcat = ws + OFF_WCAT;
    float* bcat = ws + OFF_BCAT;
    float* s1   = ws + OFF_S1;
    float* sh1  = ws + OFF_SH1;
    float* wc1t = ws + OFF_WC1T;
    float* b2f  = ws + OFF_B2F;
    float* xcat = ws + OFF_XCAT;
    float* tbuf = ws + OFF_TBUF;

    kprep<<<125, 256, 0, stream>>>(w1, b1, w2, b2, w3, b3,
                                   bn1g, bn1b, bn1m, bn1v, wcw1,
                                   bn2g, bn2b, bn2m, bn2v, ws);
    kconvA<<<392, 256, 0, stream>>>(x, wcat, bcat, xcat);
    kwmap_t<<<392, 512, 0, stream>>>(xcat, s1, sh1, wc1t, b2f, tbuf);
    dim3 gC(13, 8, 8);
    kaggr<<<gC, 256, 0, stream>>>(xcat, tbuf, wcw2, bcw2, (float*)d_out);
}